// Round 4
// baseline (69.007 us; speedup 1.0000x reference)
//
#include <hip/hip_runtime.h>

#define N_ELEM (1 << 20)
#define K 256
#define BLOCK 256
#define EPT 16
#define GRID (N_ELEM / (BLOCK * EPT))   // 256 blocks -> 1 block/CU

// Single fused kernel: every block (a) issues its x loads, (b) rank-sorts the
// 256 centers while those loads are in flight (centers[j] is wave-uniform ->
// scalar s_load batches, VALU-only rank loop), (c) binary-searches 16
// elements/thread against the sorted LDS codebook.
__global__ __launch_bounds__(BLOCK) void kmeans_fused_kernel(
    const float* __restrict__ x,
    const float* __restrict__ centers,
    int*         __restrict__ out)
{
    __shared__ float s_val[K];
    __shared__ alignas(8) float2 s_pair[K];
    const int t = threadIdx.x;
    const int base = (blockIdx.x * BLOCK + t) * EPT;

    // (a) issue global x loads first; sort below overlaps their latency
    float4 v0 = *reinterpret_cast<const float4*>(x + base);
    float4 v1 = *reinterpret_cast<const float4*>(x + base + 4);
    float4 v2 = *reinterpret_cast<const float4*>(x + base + 8);
    float4 v3 = *reinterpret_cast<const float4*>(x + base + 12);

    // (b) rank sort: thread t places centers[t] at slot rank(t); stable via j<t
    const float c = centers[t];          // per-lane (coalesced vector load)
    int rank = 0;
#pragma unroll 16
    for (int j = 0; j < K; ++j) {
        const float cj = centers[j];     // wave-uniform -> s_load, sits in SGPR
        rank += ((cj < c) || (cj == c && j < t)) ? 1 : 0;
    }
    s_val[rank]  = c;
    s_pair[rank] = make_float2(c, __int_as_float(t));
    __syncthreads();

    // wave-uniform probe values for levels s=128,64,32 (7 distinct indices)
    const float v127 = s_val[127];
    const float v63  = s_val[63],  v191 = s_val[191];
    const float v31  = s_val[31],  v95  = s_val[95];
    const float v159 = s_val[159], v223 = s_val[223];

    float xs[EPT] = {v0.x, v0.y, v0.z, v0.w, v1.x, v1.y, v1.z, v1.w,
                     v2.x, v2.y, v2.z, v2.w, v3.x, v3.y, v3.z, v3.w};
    int res[EPT];

    // (c) branchless lower_bound + two-neighbor tie-break (exact argmin
    // semantics: fp32 distances weakly unimodal over sorted centers; exact
    // tie -> smaller original index = first occurrence)
#pragma unroll
    for (int e = 0; e < EPT; ++e) {
        const float xv = xs[e];

        int pos = (v127 < xv) ? 128 : 0;
        const float la = (pos & 128) ? v191 : v63;
        pos += (la < xv) ? 64 : 0;
        const float lb = (pos & 64) ? ((pos & 128) ? v223 : v95)
                                    : ((pos & 128) ? v159 : v31);
        pos += (lb < xv) ? 32 : 0;

#pragma unroll
        for (int s = 16; s > 0; s >>= 1)
            pos += (s_val[pos + s - 1] < xv) ? s : 0;
        pos += (s_val[pos] < xv) ? 1 : 0;          // pos in [0,256]

        const int il = (pos > 0) ? pos - 1 : 0;
        const int ir = (pos < K) ? pos     : K - 1;
        const float2 pl = s_pair[il];
        const float2 pr = s_pair[ir];
        const float dl = fabsf(xv - pl.x);
        const float dr = fabsf(xv - pr.x);
        const int ol  = __float_as_int(pl.y);
        const int orr = __float_as_int(pr.y);
        res[e] = (dl < dr) ? ol : ((dr < dl) ? orr : min(ol, orr));
    }

    *reinterpret_cast<int4*>(out + base)      = make_int4(res[0],  res[1],  res[2],  res[3]);
    *reinterpret_cast<int4*>(out + base + 4)  = make_int4(res[4],  res[5],  res[6],  res[7]);
    *reinterpret_cast<int4*>(out + base + 8)  = make_int4(res[8],  res[9],  res[10], res[11]);
    *reinterpret_cast<int4*>(out + base + 12) = make_int4(res[12], res[13], res[14], res[15]);
}

extern "C" void kernel_launch(void* const* d_in, const int* in_sizes, int n_in,
                              void* d_out, int out_size, void* d_ws, size_t ws_size,
                              hipStream_t stream)
{
    const float* x       = (const float*)d_in[0];
    const float* centers = (const float*)d_in[1];
    int*         out     = (int*)d_out;

    kmeans_fused_kernel<<<GRID, BLOCK, 0, stream>>>(x, centers, out);
}

// Round 5
// 67.599 us; speedup vs baseline: 1.0208x; 1.0208x over previous
//
#include <hip/hip_runtime.h>

#define N_ELEM (1 << 20)
#define K 256
#define BLOCK 256
#define EPT 4
#define GRID (N_ELEM / (BLOCK * EPT))   // 1024 blocks -> 4 blocks/CU, 16 waves/CU

// Best-measured structure (R2, 67.62 us): small sort kernel + bsearch kernel.
// ~63 us of dur_us is harness floor (268 MB ws re-poison fills at ~41 us);
// kernel-side is ~4.6 us, within ~2 us of its own VALU/LDS/HBM roofline.

// d_ws layout: float sorted_val[256] | int sorted_orig_idx[256]

// Rank sort: thread t's center goes to slot rank(t). Stable: ties broken by
// original index, so duplicates (if any) keep ascending original order.
__global__ __launch_bounds__(K) void sort_centers_kernel(
    const float* __restrict__ centers,
    float* __restrict__ ws_val,
    int*   __restrict__ ws_idx)
{
    __shared__ float sc[K];
    const int t = threadIdx.x;
    const float c = centers[t];
    sc[t] = c;
    __syncthreads();

    int rank = 0;
#pragma unroll 8
    for (int j = 0; j < K; ++j) {
        float cj = sc[j];
        rank += (cj < c) || (cj == c && j < t);
    }
    ws_val[rank] = c;
    ws_idx[rank] = t;
}

__global__ __launch_bounds__(BLOCK) void argmin_bsearch_kernel(
    const float* __restrict__ x,
    const float* __restrict__ ws_val,
    const int*   __restrict__ ws_idx,
    int*         __restrict__ out)
{
    __shared__ float s_val[K];
    __shared__ int   s_idx[K];
    const int t = threadIdx.x;
    s_val[t] = ws_val[t];
    s_idx[t] = ws_idx[t];
    __syncthreads();

    const int base = (blockIdx.x * BLOCK + t) * EPT;
    float4 v = *reinterpret_cast<const float4*>(x + base);
    float xs[EPT] = {v.x, v.y, v.z, v.w};
    int res[EPT];

#pragma unroll
    for (int e = 0; e < EPT; ++e) {
        const float xv = xs[e];
        // branchless lower_bound: pos = #centers < xv, in [0,256]
        int pos = 0;
#pragma unroll
        for (int s = 128; s > 0; s >>= 1)
            pos += (s_val[pos + s - 1] < xv) ? s : 0;   // pos <= 255 after loop
        pos += (s_val[pos] < xv) ? 1 : 0;

        // nearest is one of the two straddling neighbors (fp32 distances are
        // weakly unimodal over sorted centers); exact tie -> smaller orig idx
        const int il = (pos > 0)  ? pos - 1 : 0;
        const int ir = (pos < K)  ? pos     : K - 1;
        const float dl = fabsf(xv - s_val[il]);
        const float dr = fabsf(xv - s_val[ir]);
        const int ol = s_idx[il], orr = s_idx[ir];
        res[e] = (dl < dr) ? ol : ((dr < dl) ? orr : min(ol, orr));
    }

    *reinterpret_cast<int4*>(out + base) = make_int4(res[0], res[1], res[2], res[3]);
}

extern "C" void kernel_launch(void* const* d_in, const int* in_sizes, int n_in,
                              void* d_out, int out_size, void* d_ws, size_t ws_size,
                              hipStream_t stream)
{
    const float* x       = (const float*)d_in[0];
    const float* centers = (const float*)d_in[1];
    int*         out     = (int*)d_out;

    float* ws_val = (float*)d_ws;
    int*   ws_idx = (int*)(ws_val + K);

    sort_centers_kernel<<<1, K, 0, stream>>>(centers, ws_val, ws_idx);
    argmin_bsearch_kernel<<<GRID, BLOCK, 0, stream>>>(x, ws_val, ws_idx, out);
}